// Round 5
// baseline (514.899 us; speedup 1.0000x reference)
//
#include <hip/hip_runtime.h>
#include <hip/hip_bf16.h>
#include <math.h>

#define D_MODEL 1024
#define D_FF    4096
#define N_HEADS 16
#define SEQ     1000
#define BATCH   8
#define M_TOK   (BATCH * SEQ)   // 8000 tokens

typedef __bf16 bf16x8_t __attribute__((ext_vector_type(8)));
typedef short  short8_t __attribute__((ext_vector_type(8)));
typedef float  f32x4_t  __attribute__((ext_vector_type(4)));
typedef float  f32x16_t __attribute__((ext_vector_type(16)));

__device__ __forceinline__ f32x4_t mfma_bf16(short8_t a, short8_t b, f32x4_t c) {
    return __builtin_amdgcn_mfma_f32_16x16x32_bf16(
        __builtin_bit_cast(bf16x8_t, a), __builtin_bit_cast(bf16x8_t, b), c, 0, 0, 0);
}

__device__ __forceinline__ f32x16_t mfma32_bf16(short8_t a, short8_t b, f32x16_t c) {
    return __builtin_amdgcn_mfma_f32_32x32x16_bf16(
        __builtin_bit_cast(bf16x8_t, a), __builtin_bit_cast(bf16x8_t, b), c, 0, 0, 0);
}

// fp32 -> bf16 round-to-nearest-even
__device__ __forceinline__ unsigned short f2bf(float f) {
    union { float f; unsigned u; } x; x.f = f;
    unsigned r = (x.u + 0x7fffu + ((x.u >> 16) & 1u)) >> 16;
    return (unsigned short)r;
}

// fast GELU (tanh form): max abs dev vs exact erf-GELU ~3e-4, below bf16 rounding
__device__ __forceinline__ float gelu_fast(float v) {
    float z = 1.5957691216f * v * fmaf(0.044715f, v * v, 1.0f);
    float e = __expf(-z);                       // v_exp_f32
    return v * __builtin_amdgcn_rcpf(1.0f + e); // v_rcp_f32
}

// async global(16B/lane) -> LDS (wave-uniform base + lane*16)
__device__ __forceinline__ void gload_lds16(const void* g, void* l) {
    __builtin_amdgcn_global_load_lds(
        (const __attribute__((address_space(1))) unsigned int*)g,
        (__attribute__((address_space(3))) unsigned int*)l, 16, 0, 0);
}

// ---------------------------------------------------------------------------
// Weight transpose+convert: 4 square d x d weights in one launch (blockIdx.z)
// ---------------------------------------------------------------------------
__global__ __launch_bounds__(256) void wtrans4_kernel(
    const float* __restrict__ wa, const float* __restrict__ wb,
    const float* __restrict__ wc, const float* __restrict__ wd,
    unsigned short* __restrict__ oa, unsigned short* __restrict__ ob,
    unsigned short* __restrict__ oc, unsigned short* __restrict__ od) {
    __shared__ float tile[32][33];
    int z = blockIdx.z;
    const float* w = z == 0 ? wa : z == 1 ? wb : z == 2 ? wc : wd;
    unsigned short* wt = z == 0 ? oa : z == 1 ? ob : z == 2 ? oc : od;
    int n0 = blockIdx.x * 32, k0 = blockIdx.y * 32;
    int tx = threadIdx.x, ty = threadIdx.y;  // 32 x 8
#pragma unroll
    for (int i = 0; i < 4; ++i)
        tile[ty + i * 8][tx] = w[(size_t)(k0 + ty + i * 8) * D_MODEL + n0 + tx];
    __syncthreads();
#pragma unroll
    for (int i = 0; i < 4; ++i)
        wt[(size_t)(n0 + ty + i * 8) * D_MODEL + k0 + tx] = f2bf(tile[tx][ty + i * 8]);
}

// generic transpose+convert: W fp32 [K][N] -> Wt bf16 [N][K]
__global__ __launch_bounds__(256) void wtrans_kernel(const float* __restrict__ w,
                                                     unsigned short* __restrict__ wt,
                                                     int Kd, int Nd) {
    __shared__ float tile[32][33];
    int n0 = blockIdx.x * 32, k0 = blockIdx.y * 32;
    int tx = threadIdx.x, ty = threadIdx.y;
#pragma unroll
    for (int i = 0; i < 4; ++i)
        tile[ty + i * 8][tx] = w[(size_t)(k0 + ty + i * 8) * Nd + n0 + tx];
    __syncthreads();
#pragma unroll
    for (int i = 0; i < 4; ++i)
        wt[(size_t)(n0 + ty + i * 8) * Kd + k0 + tx] = f2bf(tile[tx][ty + i * 8]);
}

// ---------------------------------------------------------------------------
// V transpose: v bf16 [b*1000+s][h*64+dk] -> vt bf16 [b][h*64+dk][1024] (s pad 0)
// ---------------------------------------------------------------------------
__global__ __launch_bounds__(256) void vtrans_kernel(const unsigned short* __restrict__ v,
                                                     unsigned short* __restrict__ vt) {
    __shared__ unsigned short tile[32][33];
    int b = blockIdx.z;
    int c0 = blockIdx.x * 32, s0 = blockIdx.y * 32;
    int tx = threadIdx.x, ty = threadIdx.y;
#pragma unroll
    for (int i = 0; i < 4; ++i) {
        int s = s0 + ty + i * 8;
        unsigned short val = 0;
        if (s < SEQ) val = v[((size_t)b * SEQ + s) * D_MODEL + c0 + tx];
        tile[ty + i * 8][tx] = val;
    }
    __syncthreads();
#pragma unroll
    for (int i = 0; i < 4; ++i) {
        int c = c0 + ty + i * 8;
        vt[((size_t)b * D_MODEL + c) * 1024 + s0 + tx] = tile[tx][ty + i * 8];
    }
}

// ---------------------------------------------------------------------------
// LayerNorm: x fp32 [row][1024] -> out bf16, 1 block per row
// ---------------------------------------------------------------------------
__global__ __launch_bounds__(256) void ln_kernel(const float* __restrict__ x,
                                                 const float* __restrict__ g,
                                                 const float* __restrict__ beta,
                                                 unsigned short* __restrict__ out) {
    int row = blockIdx.x, tid = threadIdx.x;
    const float4 v = ((const float4*)(x + (size_t)row * D_MODEL))[tid];
    float s  = v.x + v.y + v.z + v.w;
    float s2 = v.x * v.x + v.y * v.y + v.z * v.z + v.w * v.w;
#pragma unroll
    for (int o = 32; o > 0; o >>= 1) { s += __shfl_xor(s, o, 64); s2 += __shfl_xor(s2, o, 64); }
    __shared__ float red[8];
    int wave = tid >> 6, lane = tid & 63;
    if (lane == 0) { red[wave] = s; red[wave + 4] = s2; }
    __syncthreads();
    s  = red[0] + red[1] + red[2] + red[3];
    s2 = red[4] + red[5] + red[6] + red[7];
    float mean = s * (1.0f / D_MODEL);
    float var  = s2 * (1.0f / D_MODEL) - mean * mean;
    float rstd = rsqrtf(var + 1e-5f);
    float4 gg = ((const float4*)g)[tid];
    float4 bb = ((const float4*)beta)[tid];
    ushort4 o4;
    o4.x = f2bf((v.x - mean) * rstd * gg.x + bb.x);
    o4.y = f2bf((v.y - mean) * rstd * gg.y + bb.y);
    o4.z = f2bf((v.z - mean) * rstd * gg.z + bb.z);
    o4.w = f2bf((v.w - mean) * rstd * gg.w + bb.w);
    ((ushort4*)(out + (size_t)row * D_MODEL))[tid] = o4;
}

// ---------------------------------------------------------------------------
// GEMM  C[M][N] = A[M][K] (bf16) * Bt[N][K]^T (bf16), m97 structure with
// 32x32x16 MFMA (2x2 subtiles per 64x64 wave tile; better FLOP/issue).
// ---------------------------------------------------------------------------
enum { EPI_BF16 = 0, EPI_GELU = 1, EPI_RES_F32 = 2 };

template <int EPI, int KDIM, bool FUSE3>
__global__ __launch_bounds__(256) void gemm_bt(
    const unsigned short* __restrict__ A,
    const unsigned short* __restrict__ Bt0,
    const unsigned short* __restrict__ Bt1,
    const unsigned short* __restrict__ Bt2,
    const float* __restrict__ bias,
    const float* __restrict__ resid,
    void* __restrict__ out0, void* out1, void* out2,
    int Mdim, int Ndim) {
    constexpr int K = KDIM;
    __shared__ unsigned short lda[128 * 64];
    __shared__ unsigned short ldb[128 * 64];
    int tid = threadIdx.x;
    int lane = tid & 63, wave = tid >> 6;
    int l31 = lane & 31, half = lane >> 5;
    int rt = blockIdx.y * 128;
    const unsigned short* Bt = Bt0;
    void* outp = out0;
    int ct;
    if (FUSE3) {
        int sel = blockIdx.x >> 3;
        ct = (blockIdx.x & 7) * 128;
        Bt   = sel == 0 ? Bt0  : (sel == 1 ? Bt1  : Bt2);
        outp = sel == 0 ? out0 : (sel == 1 ? out1 : out2);
    } else {
        ct = blockIdx.x * 128;
    }
    int wr = (wave >> 1) * 64, wc = (wave & 1) * 64;
    f32x16_t acc[2][2] = {};

    const unsigned short* ag[4];
    const unsigned short* bg[4];
#pragma unroll
    for (int i = 0; i < 4; ++i) {
        int gidx = tid + i * 256;
        int row = gidx >> 3, cp = gidx & 7;
        int c = cp ^ (row & 7);
        int ar = rt + row; if (ar >= Mdim) ar = Mdim - 1;
        ag[i] = A  + (size_t)ar * K + c * 8;
        bg[i] = Bt + (size_t)(ct + row) * K + c * 8;
    }

    for (int kt = 0; kt < K / 64; ++kt) {
        __syncthreads();
#pragma unroll
        for (int i = 0; i < 4; ++i) {
            gload_lds16(ag[i], (char*)lda + (wave * 64 + i * 256) * 16);
            gload_lds16(bg[i], (char*)ldb + (wave * 64 + i * 256) * 16);
            ag[i] += 64; bg[i] += 64;
        }
        __syncthreads();
        // 4 k-steps of 16; A row = l31, k = half*8+j (granule ks*2+half)
#pragma unroll
        for (int ks = 0; ks < 4; ++ks) {
            short8_t af[2], bfr[2];
#pragma unroll
            for (int mi = 0; mi < 2; ++mi) {
                int ra = wr + mi * 32 + l31;
                int cg = (ks * 2 + half) ^ (ra & 7);
                af[mi] = *(const short8_t*)(lda + (ra * 8 + cg) * 8);
            }
#pragma unroll
            for (int ni = 0; ni < 2; ++ni) {
                int rb = wc + ni * 32 + l31;
                int cg = (ks * 2 + half) ^ (rb & 7);
                bfr[ni] = *(const short8_t*)(ldb + (rb * 8 + cg) * 8);
            }
#pragma unroll
            for (int mi = 0; mi < 2; ++mi)
#pragma unroll
                for (int ni = 0; ni < 2; ++ni)
                    acc[mi][ni] = mfma32_bf16(af[mi], bfr[ni], acc[mi][ni]);
        }
    }

    float bias_c[2];
    if (EPI != EPI_BF16) {
#pragma unroll
        for (int ni = 0; ni < 2; ++ni) bias_c[ni] = bias[ct + wc + ni * 32 + l31];
    }

    // epilogue: 32x32 C/D layout col=lane&31, row=(reg&3)+8*(reg>>2)+4*(lane>>5)
#pragma unroll
    for (int mi = 0; mi < 2; ++mi) {
#pragma unroll
        for (int reg = 0; reg < 16; ++reg) {
            int grow = rt + wr + mi * 32 + (reg & 3) + 8 * (reg >> 2) + 4 * half;
            if (grow >= Mdim) continue;
#pragma unroll
            for (int ni = 0; ni < 2; ++ni) {
                int gcol = ct + wc + ni * 32 + l31;
                float v = acc[mi][ni][reg];
                size_t idx = (size_t)grow * Ndim + gcol;
                if (EPI == EPI_BF16) {
                    ((unsigned short*)outp)[idx] = f2bf(v);
                } else if (EPI == EPI_GELU) {
                    v += bias_c[ni];
                    ((unsigned short*)outp)[idx] = f2bf(gelu_fast(v));
                } else {
                    v += bias_c[ni] + resid[idx];
                    ((float*)outp)[idx] = v;
                }
            }
        }
    }
}

// ---------------------------------------------------------------------------
// Flash attention v3: triangle-balanced + double-buffered DMA staging.
// 1 workgroup = (b, h, q-tile PAIR {p, 7-p}): every block stages exactly 18
// K/V tiles. Wave = 32 q-rows (2 groups of 16), S^T formulation (per-lane
// softmax state, q = lane&15). One barrier per tile; stage(t+1) issued into
// the alternate LDS buffer before compute(t) so the vmcnt drain at the next
// barrier lands after ~600 cyc of compute (DMA latency hidden).
// ---------------------------------------------------------------------------
__global__ __launch_bounds__(256) void attn_kernel(
    const unsigned short* __restrict__ q,
    const unsigned short* __restrict__ k,
    const unsigned short* __restrict__ vt,
    unsigned short* __restrict__ att) {
    int p = blockIdx.x, h = blockIdx.y, b = blockIdx.z;
    int tid = threadIdx.x, lane = tid & 63, wave = tid >> 6;
    int l15 = lane & 15, quad = lane >> 4;
    __shared__ unsigned short kt_lds[2][64 * 64];   // [buf][key-row][64 k], XOR-swizzled granules
    __shared__ unsigned short vt_lds[2][64 * 64];   // [buf][dk-row][64 keys]
    __shared__ unsigned short p_lds[4][32 * 64];    // wave-private P
    unsigned short* pw = p_lds[wave];

    const int qtA = p, qtB = 7 - p;
    const int tA = 2 * qtA + 2, tB = 2 * qtB + 2, total = tA + tB;  // == 18

    // preload Q fragments for both phases
    short8_t aq[2][2][2];  // [phase][g][kc]
#pragma unroll
    for (int ph = 0; ph < 2; ++ph) {
        int qw = (ph ? qtB : qtA) * 128 + wave * 32;
#pragma unroll
        for (int g = 0; g < 2; ++g) {
            int qr = qw + g * 16 + l15; if (qr > SEQ - 1) qr = SEQ - 1;
            const unsigned short* qp = q + ((size_t)(b * SEQ + qr)) * D_MODEL + h * 64 + quad * 8;
            aq[ph][g][0] = *(const short8_t*)qp;
            aq[ph][g][1] = *(const short8_t*)(qp + 32);
        }
    }

    f32x4_t o[2][4] = {};
    float m_run[2] = {-3.0e38f, -3.0e38f};
    float l_run[2] = {0.f, 0.f};

    // stage k-tile kt into buffer bufi (K: 64 keys x 64 dims; V: 64 dims x 64 keys)
    auto stage = [&](int kt, int bufi) {
#pragma unroll
        for (int i = 0; i < 2; ++i) {
            int g2 = tid + i * 256;
            int row = g2 >> 3, cp = g2 & 7;
            int c = cp ^ (row & 7);
            int key = kt * 64 + row; int keyc = key < SEQ ? key : SEQ - 1;
            gload_lds16(k + ((size_t)(b * SEQ + keyc)) * D_MODEL + h * 64 + c * 8,
                        (char*)kt_lds[bufi] + (size_t)(wave * 64 + i * 256) * 16);
            gload_lds16(vt + ((size_t)((b * N_HEADS + h) * 64 + row)) * 1024 + kt * 64 + c * 8,
                        (char*)vt_lds[bufi] + (size_t)(wave * 64 + i * 256) * 16);
        }
    };

    // store O for a finished phase, then reset state
    auto flush = [&](int qt) {
#pragma unroll
        for (int g = 0; g < 2; ++g) {
            float linv = __builtin_amdgcn_rcpf(l_run[g]);
#pragma unroll
            for (int r = 0; r < 4; ++r) {
                float nr = __shfl(linv, quad * 4 + r, 64);
                int qg = qt * 128 + wave * 32 + g * 16 + quad * 4 + r;
                if (qg >= SEQ) continue;
#pragma unroll
                for (int db = 0; db < 4; ++db)
                    att[((size_t)(b * SEQ + qg)) * D_MODEL + h * 64 + db * 16 + l15] =
                        f2bf(o[g][db][r] * nr);
            }
        }
#pragma unroll
        for (int g = 0; g < 2; ++g) {
            m_run[g] = -3.0e38f; l_run[g] = 0.f;
#pragma unroll
            for (int db = 0; db < 4; ++db) o[g][db] = f32x4_t{0.f, 0.f, 0.f, 0.f};
        }
    };

    stage(0, 0);  // prefetch first tile of phase A

    for (int i = 0; i < total; ++i) {
        int bufi = i & 1;
        __syncthreads();  // stage(i) complete; buf bufi^1 free (compute(i-1) done)
        if (i + 1 < total) {
            int nkt = (i + 1 < tA) ? (i + 1) : (i + 1 - tA);
            stage(nkt, bufi ^ 1);
        }
        int phase = (i < tA) ? 0 : 1;
        int kt = (i < tA) ? i : i - tA;
        int qt = phase ? qtB : qtA;
        int qw = qt * 128 + wave * 32;
        const unsigned short* kl = kt_lds[bufi];
        const unsigned short* vl = vt_lds[bufi];

        if (kt * 64 <= qw + 31) {  // wave not fully masked (uniform branch)
            // K fragments (shared across both q groups)
            short8_t kf[4][2];
#pragma unroll
            for (int nb = 0; nb < 4; ++nb)
#pragma unroll
                for (int kc = 0; kc < 2; ++kc) {
                    int row = nb * 16 + l15;
                    kf[nb][kc] = *(const short8_t*)(kl + (row * 8 + ((kc * 4 + quad) ^ (row & 7))) * 8);
                }

            bool gact[2];
#pragma unroll
            for (int g = 0; g < 2; ++g) {
                gact[g] = (kt * 64 <= qw + g * 16 + 15);
                if (!gact[g]) continue;
                // S^T = K Q^T : D col = q (l15), row reg = key offset quad*4+r
                f32x4_t s[4] = {};
#pragma unroll
                for (int nb = 0; nb < 4; ++nb)
#pragma unroll
                    for (int kc = 0; kc < 2; ++kc)
                        s[nb] = mfma_bf16(kf[nb][kc], aq[phase][g][kc], s[nb]);
                int qrow = qw + g * 16 + l15;
                float sc[4][4];
#pragma unroll
                for (int nb = 0; nb < 4; ++nb)
#pragma unroll
                    for (int r = 0; r < 4; ++r) {
                        int key = kt * 64 + nb * 16 + quad * 4 + r;
                        float v = s[nb][r] * 0.125f;   // 1/sqrt(64)
                        sc[nb][r] = (key <= qrow) ? v : -1e30f;
                    }
                float mx = sc[0][0];
#pragma unroll
                for (int nb = 0; nb < 4; ++nb)
#pragma unroll
                    for (int r = 0; r < 4; ++r) mx = fmaxf(mx, sc[nb][r]);
                mx = fmaxf(mx, __shfl_xor(mx, 16, 64));
                mx = fmaxf(mx, __shfl_xor(mx, 32, 64));
                float mnew = fmaxf(m_run[g], mx);
                float alpha = __expf(m_run[g] - mnew);
                m_run[g] = mnew;
                float rs = 0.f;
#pragma unroll
                for (int nb = 0; nb < 4; ++nb)
#pragma unroll
                    for (int r = 0; r < 4; ++r) {
                        float pv = __expf(sc[nb][r] - mnew);
                        sc[nb][r] = pv;
                        rs += pv;
                    }
                rs += __shfl_xor(rs, 16, 64);
                rs += __shfl_xor(rs, 32, 64);
                l_run[g] = l_run[g] * alpha + rs;
#pragma unroll
                for (int r = 0; r < 4; ++r) {
                    float a = __shfl(alpha, quad * 4 + r, 64);
#pragma unroll
                    for (int db = 0; db < 4; ++db) o[g][db][r] *= a;
                }
                // write P row q: b64 chunks (4 keys/lane), pair-preserving swizzle
#pragma unroll
                for (int nb = 0; nb < 4; ++nb) {
                    unsigned long long pv =
                        (unsigned long long)f2bf(sc[nb][0]) |
                        ((unsigned long long)f2bf(sc[nb][1]) << 16) |
                        ((unsigned long long)f2bf(sc[nb][2]) << 32) |
                        ((unsigned long long)f2bf(sc[nb][3]) << 48);
                    int chunk = (4 * nb + quad) ^ ((l15 & 7) << 1);
                    *(unsigned long long*)(pw + (g * 16 + l15) * 64 + chunk * 4) = pv;
                }
            }
            asm volatile("s_waitcnt lgkmcnt(0)" ::: "memory");

            // V fragments (shared across groups)
            short8_t vf[4][2];
#pragma unroll
            for (int db = 0; db < 4; ++db)
#pragma unroll
                for (int kc = 0; kc < 2; ++kc) {
                    int row = db * 16 + l15;
                    vf[db][kc] = *(const short8_t*)(vl + (row * 8 + ((kc * 4 + quad) ^ (row & 7))) * 8);
                }
#pragma unroll
            for (int g = 0; g < 2; ++g) {
                if (!gact[g]) continue;
                short8_t ap[2];
#pragma unroll
                for (int kc = 0; kc < 2; ++kc)
                    ap[kc] = *(const short8_t*)(pw + (g * 16 + l15) * 64 +
                                                ((kc * 4 + quad) ^ (l15 & 7)) * 8);
#pragma unroll
                for (int db = 0; db < 4; ++db)
#pragma unroll
                    for (int kc = 0; kc < 2; ++kc)
                        o[g][db] = mfma_bf16(ap[kc], vf[db][kc], o[g][db]);
            }
        }

        if (i == tA - 1) flush(qtA);  // phase A done: store + reset state
    }
    flush(qtB);
}

// ---------------------------------------------------------------------------
extern "C" void kernel_launch(void* const* d_in, const int* in_sizes, int n_in,
                              void* d_out, int out_size, void* d_ws, size_t ws_size,
                              hipStream_t stream) {
    const float* x     = (const float*)d_in[0];
    const float* wq    = (const float*)d_in[1];
    const float* wk    = (const float*)d_in[2];
    const float* wv    = (const float*)d_in[3];
    const float* wo    = (const float*)d_in[4];
    const float* bo    = (const float*)d_in[5];
    const float* w1    = (const float*)d_in[6];
    const float* b1    = (const float*)d_in[7];
    const float* w2    = (const float*)d_in[8];
    const float* b2    = (const float*)d_in[9];
    const float* g1    = (const float*)d_in[10];
    const float* beta1 = (const float*)d_in[11];
    const float* g2    = (const float*)d_in[12];
    const float* beta2 = (const float*)d_in[13];
    float* out = (float*)d_out;
    char* ws = (char*)d_ws;

    const size_t SZ_MD_BF16 = (size_t)M_TOK * D_MODEL * 2;  // 16,384,000
    unsigned short* h1  = (unsigned short*)(ws);                       // also h2 (alias)
    unsigned short* qb  = (unsigned short*)(ws + SZ_MD_BF16);
    unsigned short* kb  = (unsigned short*)(ws + 2 * SZ_MD_BF16);
    unsigned short* vb  = (unsigned short*)(ws + 3 * SZ_MD_BF16);
    unsigned short* atb = (unsigned short*)(ws + 4 * SZ_MD_BF16);
    unsigned short* ffb = qb;                                          // alias: q..att dead after WO
    size_t off = 5 * SZ_MD_BF16;
    unsigned short* vtb = (unsigned short*)(ws + off); off += (size_t)BATCH * D_MODEL * 1024 * 2; // 16.78MB
    float* x1 = (float*)(ws + off); off += (size_t)M_TOK * D_MODEL * 4;
    unsigned short* wqt = (unsigned short*)(ws + off); off += (size_t)D_MODEL * D_MODEL * 2;
    unsigned short* wkt = (unsigned short*)(ws + off); off += (size_t)D_MODEL * D_MODEL * 2;
    unsigned short* wvt = (unsigned short*)(ws + off); off += (size_t)D_MODEL * D_MODEL * 2;
    unsigned short* wot = (unsigned short*)(ws + off); off += (size_t)D_MODEL * D_MODEL * 2;
    unsigned short* w1t = (unsigned short*)(ws + off); off += (size_t)D_MODEL * D_FF * 2;
    unsigned short* w2t = (unsigned short*)(ws + off); off += (size_t)D_MODEL * D_FF * 2;

    dim3 tb(32, 8);
    wtrans4_kernel<<<dim3(32, 32, 4), tb, 0, stream>>>(wq, wk, wv, wo, wqt, wkt, wvt, wot);
    wtrans_kernel<<<dim3(128, 32), tb, 0, stream>>>(w1, w1t, D_MODEL, D_FF);
    wtrans_kernel<<<dim3(32, 128), tb, 0, stream>>>(w2, w2t, D_FF, D_MODEL);

    ln_kernel<<<M_TOK, 256, 0, stream>>>(x, g1, beta1, h1);

    const int MT = (M_TOK + 127) / 128;  // 63
    gemm_bt<EPI_BF16, D_MODEL, true><<<dim3(24, MT), 256, 0, stream>>>(
        h1, wqt, wkt, wvt, nullptr, nullptr, qb, kb, vb, M_TOK, D_MODEL);

    vtrans_kernel<<<dim3(32, 32, 8), tb, 0, stream>>>(vb, vtb);

    attn_kernel<<<dim3(4, N_HEADS, BATCH), 256, 0, stream>>>(qb, kb, vtb, atb);

    gemm_bt<EPI_RES_F32, D_MODEL, false><<<dim3(8, MT), 256, 0, stream>>>(
        atb, wot, nullptr, nullptr, bo, x, x1, nullptr, nullptr, M_TOK, D_MODEL);

    ln_kernel<<<M_TOK, 256, 0, stream>>>(x1, g2, beta2, h1);  // h2 aliases h1

    gemm_bt<EPI_GELU, D_MODEL, false><<<dim3(32, MT), 256, 0, stream>>>(
        h1, w1t, nullptr, nullptr, b1, nullptr, ffb, nullptr, nullptr, M_TOK, D_FF);

    gemm_bt<EPI_RES_F32, D_FF, false><<<dim3(8, MT), 256, 0, stream>>>(
        ffb, w2t, nullptr, nullptr, b2, x1, out, nullptr, nullptr, M_TOK, D_MODEL);
}

// Round 6
// 501.484 us; speedup vs baseline: 1.0267x; 1.0267x over previous
//
#include <hip/hip_runtime.h>
#include <hip/hip_bf16.h>
#include <math.h>

#define D_MODEL 1024
#define D_FF    4096
#define N_HEADS 16
#define SEQ     1000
#define BATCH   8
#define M_TOK   (BATCH * SEQ)   // 8000 tokens

typedef __bf16 bf16x8_t __attribute__((ext_vector_type(8)));
typedef short  short8_t __attribute__((ext_vector_type(8)));
typedef float  f32x4_t  __attribute__((ext_vector_type(4)));

__device__ __forceinline__ f32x4_t mfma_bf16(short8_t a, short8_t b, f32x4_t c) {
    return __builtin_amdgcn_mfma_f32_16x16x32_bf16(
        __builtin_bit_cast(bf16x8_t, a), __builtin_bit_cast(bf16x8_t, b), c, 0, 0, 0);
}

// fp32 -> bf16 round-to-nearest-even
__device__ __forceinline__ unsigned short f2bf(float f) {
    union { float f; unsigned u; } x; x.f = f;
    unsigned r = (x.u + 0x7fffu + ((x.u >> 16) & 1u)) >> 16;
    return (unsigned short)r;
}

// fast GELU (tanh form): max abs dev vs exact erf-GELU ~3e-4, below bf16 rounding
__device__ __forceinline__ float gelu_fast(float v) {
    float z = 1.5957691216f * v * fmaf(0.044715f, v * v, 1.0f);
    float e = __expf(-z);                       // v_exp_f32
    return v * __builtin_amdgcn_rcpf(1.0f + e); // v_rcp_f32
}

// async global(16B/lane) -> LDS (wave-uniform base + lane*16)
__device__ __forceinline__ void gload_lds16(const void* g, void* l) {
    __builtin_amdgcn_global_load_lds(
        (const __attribute__((address_space(1))) unsigned int*)g,
        (__attribute__((address_space(3))) unsigned int*)l, 16, 0, 0);
}

// ---------------------------------------------------------------------------
// Prep: all 6 weight transposes (fp32 [K][N] -> bf16 [N][K]) + LN1, one launch.
// blocks 0..4095: wq/wk/wv/wo (1024 each); 4096..8191: w1; 8192..12287: w2;
// 12288..20287: LayerNorm rows.
// ---------------------------------------------------------------------------
__global__ __launch_bounds__(256) void prep_kernel(
    const float* __restrict__ wq, const float* __restrict__ wk,
    const float* __restrict__ wv, const float* __restrict__ wo,
    const float* __restrict__ w1, const float* __restrict__ w2,
    unsigned short* __restrict__ wqt, unsigned short* __restrict__ wkt,
    unsigned short* __restrict__ wvt, unsigned short* __restrict__ wot,
    unsigned short* __restrict__ w1t, unsigned short* __restrict__ w2t,
    const float* __restrict__ x, const float* __restrict__ g1,
    const float* __restrict__ beta1, unsigned short* __restrict__ h1) {
    int id = blockIdx.x;
    __shared__ float tile[32][33];
    __shared__ float red[8];
    if (id >= 12288) {
        // ---- LayerNorm row ----
        int row = id - 12288, tid = threadIdx.x;
        const float4 v = ((const float4*)(x + (size_t)row * D_MODEL))[tid];
        float s  = v.x + v.y + v.z + v.w;
        float s2 = v.x * v.x + v.y * v.y + v.z * v.z + v.w * v.w;
#pragma unroll
        for (int o = 32; o > 0; o >>= 1) { s += __shfl_xor(s, o, 64); s2 += __shfl_xor(s2, o, 64); }
        int wave = tid >> 6, lane = tid & 63;
        if (lane == 0) { red[wave] = s; red[wave + 4] = s2; }
        __syncthreads();
        s  = red[0] + red[1] + red[2] + red[3];
        s2 = red[4] + red[5] + red[6] + red[7];
        float mean = s * (1.0f / D_MODEL);
        float var  = s2 * (1.0f / D_MODEL) - mean * mean;
        float rstd = rsqrtf(var + 1e-5f);
        float4 gg = ((const float4*)g1)[tid];
        float4 bb = ((const float4*)beta1)[tid];
        ushort4 o4;
        o4.x = f2bf((v.x - mean) * rstd * gg.x + bb.x);
        o4.y = f2bf((v.y - mean) * rstd * gg.y + bb.y);
        o4.z = f2bf((v.z - mean) * rstd * gg.z + bb.z);
        o4.w = f2bf((v.w - mean) * rstd * gg.w + bb.w);
        ((ushort4*)(h1 + (size_t)row * D_MODEL))[tid] = o4;
        return;
    }
    // ---- weight transpose ----
    const float* w; unsigned short* wt; int Kd, Nd, bx, by;
    if (id < 4096) {
        int z = id >> 10, t = id & 1023;
        w  = z == 0 ? wq  : z == 1 ? wk  : z == 2 ? wv  : wo;
        wt = z == 0 ? wqt : z == 1 ? wkt : z == 2 ? wvt : wot;
        Kd = 1024; Nd = 1024; bx = t & 31; by = t >> 5;
    } else if (id < 8192) {
        int t = id - 4096;
        w = w1; wt = w1t; Kd = 1024; Nd = 4096; bx = t & 127; by = t >> 7;
    } else {
        int t = id - 8192;
        w = w2; wt = w2t; Kd = 4096; Nd = 1024; bx = t & 31; by = t >> 5;
    }
    int n0 = bx * 32, k0 = by * 32;
    int tx = threadIdx.x & 31, ty = threadIdx.x >> 5;  // 32 x 8
#pragma unroll
    for (int i = 0; i < 4; ++i)
        tile[ty + i * 8][tx] = w[(size_t)(k0 + ty + i * 8) * Nd + n0 + tx];
    __syncthreads();
#pragma unroll
    for (int i = 0; i < 4; ++i)
        wt[(size_t)(n0 + ty + i * 8) * Kd + k0 + tx] = f2bf(tile[tx][ty + i * 8]);
}

// ---------------------------------------------------------------------------
// V transpose: v bf16 [b*1000+s][h*64+dk] -> vt bf16 [b][h*64+dk][1024] (s pad 0)
// ---------------------------------------------------------------------------
__global__ __launch_bounds__(256) void vtrans_kernel(const unsigned short* __restrict__ v,
                                                     unsigned short* __restrict__ vt) {
    __shared__ unsigned short tile[32][33];
    int b = blockIdx.z;
    int c0 = blockIdx.x * 32, s0 = blockIdx.y * 32;
    int tx = threadIdx.x, ty = threadIdx.y;
#pragma unroll
    for (int i = 0; i < 4; ++i) {
        int s = s0 + ty + i * 8;
        unsigned short val = 0;
        if (s < SEQ) val = v[((size_t)b * SEQ + s) * D_MODEL + c0 + tx];
        tile[ty + i * 8][tx] = val;
    }
    __syncthreads();
#pragma unroll
    for (int i = 0; i < 4; ++i) {
        int c = c0 + ty + i * 8;
        vt[((size_t)b * D_MODEL + c) * 1024 + s0 + tx] = tile[tx][ty + i * 8];
    }
}

// ---------------------------------------------------------------------------
// LayerNorm: x fp32 [row][1024] -> out bf16, 1 block per row
// ---------------------------------------------------------------------------
__global__ __launch_bounds__(256) void ln_kernel(const float* __restrict__ x,
                                                 const float* __restrict__ g,
                                                 const float* __restrict__ beta,
                                                 unsigned short* __restrict__ out) {
    int row = blockIdx.x, tid = threadIdx.x;
    const float4 v = ((const float4*)(x + (size_t)row * D_MODEL))[tid];
    float s  = v.x + v.y + v.z + v.w;
    float s2 = v.x * v.x + v.y * v.y + v.z * v.z + v.w * v.w;
#pragma unroll
    for (int o = 32; o > 0; o >>= 1) { s += __shfl_xor(s, o, 64); s2 += __shfl_xor(s2, o, 64); }
    __shared__ float red[8];
    int wave = tid >> 6, lane = tid & 63;
    if (lane == 0) { red[wave] = s; red[wave + 4] = s2; }
    __syncthreads();
    s  = red[0] + red[1] + red[2] + red[3];
    s2 = red[4] + red[5] + red[6] + red[7];
    float mean = s * (1.0f / D_MODEL);
    float var  = s2 * (1.0f / D_MODEL) - mean * mean;
    float rstd = rsqrtf(var + 1e-5f);
    float4 gg = ((const float4*)g)[tid];
    float4 bb = ((const float4*)beta)[tid];
    ushort4 o4;
    o4.x = f2bf((v.x - mean) * rstd * gg.x + bb.x);
    o4.y = f2bf((v.y - mean) * rstd * gg.y + bb.y);
    o4.z = f2bf((v.z - mean) * rstd * gg.z + bb.z);
    o4.w = f2bf((v.w - mean) * rstd * gg.w + bb.w);
    ((ushort4*)(out + (size_t)row * D_MODEL))[tid] = o4;
}

// ---------------------------------------------------------------------------
// GEMM  C[M][N] = A[M][K] (bf16) * Bt[N][K]^T (bf16).
// 16x16x32 MFMA (proven 0-conflict), 128x128 tile, BK=64, 4 waves.
// DOUBLE-BUFFERED DMA staging: stage(kt+1) issued before compute(kt); the
// vmcnt(0) drain at the single per-iter barrier lands after a full compute
// phase, hiding the global_load_lds latency (R4-attn-proven pattern).
// ---------------------------------------------------------------------------
enum { EPI_BF16 = 0, EPI_GELU = 1, EPI_RES_F32 = 2 };

template <int EPI, int KDIM, bool FUSE3>
__global__ __launch_bounds__(256) void gemm_bt(
    const unsigned short* __restrict__ A,
    const unsigned short* __restrict__ Bt0,
    const unsigned short* __restrict__ Bt1,
    const unsigned short* __restrict__ Bt2,
    const float* __restrict__ bias,
    const float* __restrict__ resid,
    void* __restrict__ out0, void* out1, void* out2,
    int Mdim, int Ndim) {
    constexpr int K = KDIM;
    constexpr int NKT = K / 64;
    __shared__ unsigned short lda[2][128 * 64];
    __shared__ unsigned short ldb[2][128 * 64];
    int tid = threadIdx.x;
    int lane = tid & 63, wave = tid >> 6;
    int l15 = lane & 15, quad = lane >> 4;
    int rt = blockIdx.y * 128;
    const unsigned short* Bt = Bt0;
    void* outp = out0;
    int ct;
    if (FUSE3) {
        int sel = blockIdx.x >> 3;
        ct = (blockIdx.x & 7) * 128;
        Bt   = sel == 0 ? Bt0  : (sel == 1 ? Bt1  : Bt2);
        outp = sel == 0 ? out0 : (sel == 1 ? out1 : out2);
    } else {
        ct = blockIdx.x * 128;
    }
    int wr = (wave >> 1) * 64, wc = (wave & 1) * 64;
    f32x4_t acc[4][4] = {};

    // per-lane staging source pointers (kt-invariant part)
    const unsigned short* ag[4];
    const unsigned short* bg[4];
#pragma unroll
    for (int i = 0; i < 4; ++i) {
        int gidx = tid + i * 256;        // granule 0..1023
        int row = gidx >> 3, cp = gidx & 7;
        int c = cp ^ (row & 7);          // swizzled source granule
        int ar = rt + row; if (ar >= Mdim) ar = Mdim - 1;
        ag[i] = A  + (size_t)ar * K + c * 8;
        bg[i] = Bt + (size_t)(ct + row) * K + c * 8;
    }

    auto stage = [&](int kt, int bufi) {
#pragma unroll
        for (int i = 0; i < 4; ++i) {
            gload_lds16(ag[i] + kt * 64, (char*)lda[bufi] + (wave * 64 + i * 256) * 16);
            gload_lds16(bg[i] + kt * 64, (char*)ldb[bufi] + (wave * 64 + i * 256) * 16);
        }
    };

    stage(0, 0);
    for (int kt = 0; kt < NKT; ++kt) {
        int bufi = kt & 1;
        __syncthreads();              // stage(kt) done; compute(kt-1) done
        if (kt + 1 < NKT) stage(kt + 1, bufi ^ 1);
        const unsigned short* la = lda[bufi];
        const unsigned short* lb = ldb[bufi];
#pragma unroll
        for (int kc = 0; kc < 2; ++kc) {
            short8_t af[4], bfr[4];
#pragma unroll
            for (int mi = 0; mi < 4; ++mi) {
                int ra = wr + mi * 16 + l15;
                int cg = (kc * 4 + quad) ^ (ra & 7);
                af[mi] = *(const short8_t*)(la + (ra * 8 + cg) * 8);
            }
#pragma unroll
            for (int ni = 0; ni < 4; ++ni) {
                int rb = wc + ni * 16 + l15;
                int cg = (kc * 4 + quad) ^ (rb & 7);
                bfr[ni] = *(const short8_t*)(lb + (rb * 8 + cg) * 8);
            }
#pragma unroll
            for (int mi = 0; mi < 4; ++mi)
#pragma unroll
                for (int ni = 0; ni < 4; ++ni)
                    acc[mi][ni] = mfma_bf16(af[mi], bfr[ni], acc[mi][ni]);
        }
    }

    float bias_c[4];
    if (EPI != EPI_BF16) {
#pragma unroll
        for (int ni = 0; ni < 4; ++ni) bias_c[ni] = bias[ct + wc + ni * 16 + l15];
    }

    // epilogue: C/D layout col=lane&15, row=quad*4+reg
#pragma unroll
    for (int mi = 0; mi < 4; ++mi) {
#pragma unroll
        for (int r = 0; r < 4; ++r) {
            int grow = rt + wr + mi * 16 + quad * 4 + r;
            if (grow >= Mdim) continue;
#pragma unroll
            for (int ni = 0; ni < 4; ++ni) {
                int gcol = ct + wc + ni * 16 + l15;
                float v = acc[mi][ni][r];
                size_t idx = (size_t)grow * Ndim + gcol;
                if (EPI == EPI_BF16) {
                    ((unsigned short*)outp)[idx] = f2bf(v);
                } else if (EPI == EPI_GELU) {
                    v += bias_c[ni];
                    ((unsigned short*)outp)[idx] = f2bf(gelu_fast(v));
                } else {
                    v += bias_c[ni] + resid[idx];
                    ((float*)outp)[idx] = v;
                }
            }
        }
    }
}

// ---------------------------------------------------------------------------
// Flash attention v3: triangle-balanced + double-buffered DMA staging.
// (unchanged from R4 — proven)
// ---------------------------------------------------------------------------
__global__ __launch_bounds__(256) void attn_kernel(
    const unsigned short* __restrict__ q,
    const unsigned short* __restrict__ k,
    const unsigned short* __restrict__ vt,
    unsigned short* __restrict__ att) {
    int p = blockIdx.x, h = blockIdx.y, b = blockIdx.z;
    int tid = threadIdx.x, lane = tid & 63, wave = tid >> 6;
    int l15 = lane & 15, quad = lane >> 4;
    __shared__ unsigned short kt_lds[2][64 * 64];
    __shared__ unsigned short vt_lds[2][64 * 64];
    __shared__ unsigned short p_lds[4][32 * 64];
    unsigned short* pw = p_lds[wave];

    const int qtA = p, qtB = 7 - p;
    const int tA = 2 * qtA + 2, tB = 2 * qtB + 2, total = tA + tB;  // == 18

    short8_t aq[2][2][2];  // [phase][g][kc]
#pragma unroll
    for (int ph = 0; ph < 2; ++ph) {
        int qw = (ph ? qtB : qtA) * 128 + wave * 32;
#pragma unroll
        for (int g = 0; g < 2; ++g) {
            int qr = qw + g * 16 + l15; if (qr > SEQ - 1) qr = SEQ - 1;
            const unsigned short* qp = q + ((size_t)(b * SEQ + qr)) * D_MODEL + h * 64 + quad * 8;
            aq[ph][g][0] = *(const short8_t*)qp;
            aq[ph][g][1] = *(const short8_t*)(qp + 32);
        }
    }

    f32x4_t o[2][4] = {};
    float m_run[2] = {-3.0e38f, -3.0e38f};
    float l_run[2] = {0.f, 0.f};

    auto stage = [&](int kt, int bufi) {
#pragma unroll
        for (int i = 0; i < 2; ++i) {
            int g2 = tid + i * 256;
            int row = g2 >> 3, cp = g2 & 7;
            int c = cp ^ (row & 7);
            int key = kt * 64 + row; int keyc = key < SEQ ? key : SEQ - 1;
            gload_lds16(k + ((size_t)(b * SEQ + keyc)) * D_MODEL + h * 64 + c * 8,
                        (char*)kt_lds[bufi] + (size_t)(wave * 64 + i * 256) * 16);
            gload_lds16(vt + ((size_t)((b * N_HEADS + h) * 64 + row)) * 1024 + kt * 64 + c * 8,
                        (char*)vt_lds[bufi] + (size_t)(wave * 64 + i * 256) * 16);
        }
    };

    auto flush = [&](int qt) {
#pragma unroll
        for (int g = 0; g < 2; ++g) {
            float linv = __builtin_amdgcn_rcpf(l_run[g]);
#pragma unroll
            for (int r = 0; r < 4; ++r) {
                float nr = __shfl(linv, quad * 4 + r, 64);
                int qg = qt * 128 + wave * 32 + g * 16 + quad * 4 + r;
                if (qg >= SEQ) continue;
#pragma unroll
                for (int db = 0; db < 4; ++db)
                    att[((size_t)(b * SEQ + qg)) * D_MODEL + h * 64 + db * 16 + l15] =
                        f2bf(o[g][db][r] * nr);
            }
        }
#pragma unroll
        for (int g = 0; g < 2; ++g) {
            m_run[g] = -3.0e38f; l_run[g] = 0.f;
#pragma unroll
            for (int db = 0; db < 4; ++db) o[g][db] = f32x4_t{0.f, 0.f, 0.f, 0.f};
        }
    };

    stage(0, 0);

    for (int i = 0; i < total; ++i) {
        int bufi = i & 1;
        __syncthreads();
        if (i + 1 < total) {
            int nkt = (i + 1 < tA) ? (i + 1) : (i + 1 - tA);
            stage(nkt, bufi ^ 1);
        }
        int phase = (i < tA) ? 0 : 1;
        int kt = (i < tA) ? i : i - tA;
        int qt = phase ? qtB : qtA;
        int qw = qt * 128 + wave * 32;
        const unsigned short* kl = kt_lds[bufi];
        const unsigned short* vl = vt_lds[bufi];

        if (kt * 64 <= qw + 31) {
            short8_t kf[4][2];
#pragma unroll
            for (int nb = 0; nb < 4; ++nb)
#pragma unroll
                for (int kc = 0; kc < 2; ++kc) {
                    int row = nb * 16 + l15;
                    kf[nb][kc] = *(const short8_t*)(kl + (row * 8 + ((kc * 4 + quad) ^ (row & 7))) * 8);
                }

            bool gact[2];
#pragma unroll
            for (int g = 0; g < 2; ++g) {
                gact[g] = (kt * 64 <= qw + g * 16 + 15);
                if (!gact[g]) continue;
                f32x4_t s[4] = {};
#pragma unroll
                for (int nb = 0; nb < 4; ++nb)
#pragma unroll
                    for (int kc = 0; kc < 2; ++kc)
                        s[nb] = mfma_bf16(kf[nb][kc], aq[phase][g][kc], s[nb]);
                int qrow = qw + g * 16 + l15;
                float sc[4][4];
#pragma unroll
                for (int nb = 0; nb < 4; ++nb)
#pragma unroll
                    for (int r = 0; r < 4; ++r) {
                        int key = kt * 64 + nb * 16 + quad * 4 + r;
                        float v = s[nb][r] * 0.125f;
                        sc[nb][r] = (key <= qrow) ? v : -1e30f;
                    }
                float mx = sc[0][0];
#pragma unroll
                for (int nb = 0; nb < 4; ++nb)
#pragma unroll
                    for (int r = 0; r < 4; ++r) mx = fmaxf(mx, sc[nb][r]);
                mx = fmaxf(mx, __shfl_xor(mx, 16, 64));
                mx = fmaxf(mx, __shfl_xor(mx, 32, 64));
                float mnew = fmaxf(m_run[g], mx);
                float alpha = __expf(m_run[g] - mnew);
                m_run[g] = mnew;
                float rs = 0.f;
#pragma unroll
                for (int nb = 0; nb < 4; ++nb)
#pragma unroll
                    for (int r = 0; r < 4; ++r) {
                        float pv = __expf(sc[nb][r] - mnew);
                        sc[nb][r] = pv;
                        rs += pv;
                    }
                rs += __shfl_xor(rs, 16, 64);
                rs += __shfl_xor(rs, 32, 64);
                l_run[g] = l_run[g] * alpha + rs;
#pragma unroll
                for (int r = 0; r < 4; ++r) {
                    float a = __shfl(alpha, quad * 4 + r, 64);
#pragma unroll
                    for (int db = 0; db < 4; ++db) o[g][db][r] *= a;
                }
#pragma unroll
                for (int nb = 0; nb < 4; ++nb) {
                    unsigned long long pv =
                        (unsigned long long)f2bf(sc[nb][0]) |
                        ((unsigned long long)f2bf(sc[nb][1]) << 16) |
                        ((unsigned long long)f2bf(sc[nb][2]) << 32) |
                        ((unsigned long long)f2bf(sc[nb][3]) << 48);
                    int chunk = (4 * nb + quad) ^ ((l15 & 7) << 1);
                    *(unsigned long long*)(pw + (g * 16 + l15) * 64 + chunk * 4) = pv;
                }
            }
            asm volatile("s_waitcnt lgkmcnt(0)" ::: "memory");

            short8_t vf[4][2];
#pragma unroll
            for (int db = 0; db < 4; ++db)
#pragma unroll
                for (int kc = 0; kc < 2; ++kc) {
                    int row = db * 16 + l15;
                    vf[db][kc] = *(const short8_t*)(vl + (row * 8 + ((kc * 4 + quad) ^ (row & 7))) * 8);
                }
#pragma unroll
            for (int g = 0; g < 2; ++g) {
                if (!gact[g]) continue;
                short8_t ap[2];
#pragma unroll
                for (int kc = 0; kc < 2; ++kc)
                    ap[kc] = *(const short8_t*)(pw + (g * 16 + l15) * 64 +
                                                ((kc * 4 + quad) ^ (l15 & 7)) * 8);
#pragma unroll
                for (int db = 0; db < 4; ++db)
#pragma unroll
                    for (int kc = 0; kc < 2; ++kc)
                        o[g][db] = mfma_bf16(ap[kc], vf[db][kc], o[g][db]);
            }
        }

        if (i == tA - 1) flush(qtA);
    }
    flush(qtB);
}

// ---------------------------------------------------------------------------
extern "C" void kernel_launch(void* const* d_in, const int* in_sizes, int n_in,
                              void* d_out, int out_size, void* d_ws, size_t ws_size,
                              hipStream_t stream) {
    const float* x     = (const float*)d_in[0];
    const float* wq    = (const float*)d_in[1];
    const float* wk    = (const float*)d_in[2];
    const float* wv    = (const float*)d_in[3];
    const float* wo    = (const float*)d_in[4];
    const float* bo    = (const float*)d_in[5];
    const float* w1    = (const float*)d_in[6];
    const float* b1    = (const float*)d_in[7];
    const float* w2    = (const float*)d_in[8];
    const float* b2    = (const float*)d_in[9];
    const float* g1    = (const float*)d_in[10];
    const float* beta1 = (const float*)d_in[11];
    const float* g2    = (const float*)d_in[12];
    const float* beta2 = (const float*)d_in[13];
    float* out = (float*)d_out;
    char* ws = (char*)d_ws;

    const size_t SZ_MD_BF16 = (size_t)M_TOK * D_MODEL * 2;  // 16,384,000
    unsigned short* h1  = (unsigned short*)(ws);                       // also h2 (alias)
    unsigned short* qb  = (unsigned short*)(ws + SZ_MD_BF16);
    unsigned short* kb  = (unsigned short*)(ws + 2 * SZ_MD_BF16);
    unsigned short* vb  = (unsigned short*)(ws + 3 * SZ_MD_BF16);
    unsigned short* atb = (unsigned short*)(ws + 4 * SZ_MD_BF16);
    unsigned short* ffb = qb;                                          // alias: q..att dead after WO
    size_t off = 5 * SZ_MD_BF16;
    unsigned short* vtb = (unsigned short*)(ws + off); off += (size_t)BATCH * D_MODEL * 1024 * 2; // 16.78MB
    float* x1 = (float*)(ws + off); off += (size_t)M_TOK * D_MODEL * 4;
    unsigned short* wqt = (unsigned short*)(ws + off); off += (size_t)D_MODEL * D_MODEL * 2;
    unsigned short* wkt = (unsigned short*)(ws + off); off += (size_t)D_MODEL * D_MODEL * 2;
    unsigned short* wvt = (unsigned short*)(ws + off); off += (size_t)D_MODEL * D_MODEL * 2;
    unsigned short* wot = (unsigned short*)(ws + off); off += (size_t)D_MODEL * D_MODEL * 2;
    unsigned short* w1t = (unsigned short*)(ws + off); off += (size_t)D_MODEL * D_FF * 2;
    unsigned short* w2t = (unsigned short*)(ws + off); off += (size_t)D_MODEL * D_FF * 2;

    // all weight transposes + LN1 in one launch
    prep_kernel<<<12288 + M_TOK, 256, 0, stream>>>(
        wq, wk, wv, wo, w1, w2, wqt, wkt, wvt, wot, w1t, w2t, x, g1, beta1, h1);

    const int MT = (M_TOK + 127) / 128;  // 63
    gemm_bt<EPI_BF16, D_MODEL, true><<<dim3(24, MT), 256, 0, stream>>>(
        h1, wqt, wkt, wvt, nullptr, nullptr, qb, kb, vb, M_TOK, D_MODEL);

    dim3 tb(32, 8);
    vtrans_kernel<<<dim3(32, 32, 8), tb, 0, stream>>>(vb, vtb);

    attn_kernel<<<dim3(4, N_HEADS, BATCH), 256, 0, stream>>>(qb, kb, vtb, atb);

    gemm_bt<EPI_RES_F32, D_MODEL, false><<<dim3(8, MT), 256, 0, stream>>>(
        atb, wot, nullptr, nullptr, bo, x, x1, nullptr, nullptr, M_TOK, D_MODEL);

    ln_kernel<<<M_TOK, 256, 0, stream>>>(x1, g2, beta2, h1);  // h2 aliases h1

    gemm_bt<EPI_GELU, D_MODEL, false><<<dim3(32, MT), 256, 0, stream>>>(
        h1, w1t, nullptr, nullptr, b1, nullptr, ffb, nullptr, nullptr, M_TOK, D_FF);

    gemm_bt<EPI_RES_F32, D_FF, false><<<dim3(8, MT), 256, 0, stream>>>(
        ffb, w2t, nullptr, nullptr, b2, x1, out, nullptr, nullptr, M_TOK, D_MODEL);
}